// Round 10
// baseline (267.352 us; speedup 1.0000x reference)
//
#include <hip/hip_runtime.h>
#include <hip/hip_bf16.h>

typedef __attribute__((ext_vector_type(4))) float f32x4;
typedef __attribute__((ext_vector_type(8))) short short8;
typedef unsigned short u16;

typedef const __attribute__((address_space(1))) void* gas_ptr;
typedef __attribute__((address_space(3))) void* las_ptr;

#define HW 9216
#define NROW 2048
#define CCH 128

__device__ __forceinline__ u16 f2bf(float x) {
  unsigned u = __float_as_uint(x);
  u += 0x7fffu + ((u >> 16) & 1u);   // round-to-nearest-even
  return (u16)(u >> 16);
}

__device__ __forceinline__ float bf2f(u16 v) {
  return __uint_as_float(((unsigned)v) << 16);
}

__device__ __forceinline__ void async16(const void* g, void* l) {
  __builtin_amdgcn_global_load_lds((gas_ptr)g, (las_ptr)l, 16, 0, 0);
}

// ---------------- kernel 0: convert weights fp32 -> bf16 ----------------
__global__ __launch_bounds__(256) void wcvt_kernel(
    const float* __restrict__ wq, const float* __restrict__ wk, const float* __restrict__ wv,
    u16* __restrict__ oq, u16* __restrict__ ok, u16* __restrict__ ov) {
  int i = blockIdx.x * 256 + threadIdx.x;
  if (i < CCH * CCH) {
    oq[i] = f2bf(wq[i]);
    ok[i] = f2bf(wk[i]);
    ov[i] = f2bf(wv[i]);
  }
}

// ---------------- kernel 1 v2: projection, one of {q,k,v} per blockIdx.z ----
// (r7 verified) z=0: q = Wq*f; z=1: k = Wk*e; z=2: vt = (Wv*f)^T.
__global__ __launch_bounds__(256) void proj2_kernel(
    const float* __restrict__ f_in, const float* __restrict__ e_in,
    const u16* __restrict__ Wq, const u16* __restrict__ Wk, const u16* __restrict__ Wv,
    u16* __restrict__ q, u16* __restrict__ kmat, u16* __restrict__ vt) {
  __shared__ __align__(16) u16 smem[9216];   // 18KB: max(stage 64x128, out 128x72, outT 64x136)
  const int tid = threadIdx.x;
  const int lane = tid & 63;
  const int w = tid >> 6;                    // wave = o-band (32 rows)
  const int lr = lane & 15, lg = lane >> 4;
  const int z = blockIdx.z;
  const int b = blockIdx.y;
  const int hw0 = blockIdx.x * 64;

  const float* src = (z == 1) ? e_in : f_in;
  const u16* W = (z == 0) ? Wq : (z == 1) ? Wk : Wv;

  short8 afrag[2][4];
  #pragma unroll
  for (int m = 0; m < 2; ++m)
    #pragma unroll
    for (int kk = 0; kk < 4; ++kk)
      afrag[m][kk] = *(const short8*)(W + (w * 32 + m * 16 + lr) * CCH + kk * 32 + lg * 8);

  const size_t base = (size_t)b * CCH * HW + hw0;
  #pragma unroll
  for (int it = 0; it < 4; ++it) {
    int g = w + 4 * it;                      // c-block 0..15 (8 channels each)
    const float* sp = src + base + (size_t)(g * 8) * HW + lane;
    short8 sv;
    #pragma unroll
    for (int j = 0; j < 8; ++j) sv[j] = (short)f2bf(sp[(size_t)j * HW]);
    int gs = (g & 8) | ((g & 7) ^ (lane & 7));
    *(short8*)&smem[lane * 128 + gs * 8] = sv;
  }
  __syncthreads();

  f32x4 acc[2][4] = {};
  #pragma unroll
  for (int kk = 0; kk < 4; ++kk) {
    short8 bF[4];
    #pragma unroll
    for (int n = 0; n < 4; ++n) {
      int col = n * 16 + lr;
      int gidx = kk * 4 + lg;
      int gsw = (gidx & 8) | ((gidx & 7) ^ (col & 7));
      bF[n] = *(const short8*)&smem[col * 128 + gsw * 8];
    }
    #pragma unroll
    for (int m = 0; m < 2; ++m)
      #pragma unroll
      for (int n = 0; n < 4; ++n)
        acc[m][n] = __builtin_amdgcn_mfma_f32_16x16x32_bf16(afrag[m][kk], bF[n], acc[m][n], 0, 0, 0);
  }
  __syncthreads();   // all reads of staged tile done; reuse smem for output

  if (z < 2) {
    #pragma unroll
    for (int m = 0; m < 2; ++m)
      #pragma unroll
      for (int n = 0; n < 4; ++n) {
        int o0 = w * 32 + m * 16 + 4 * lg;
        int col = n * 16 + lr;
        #pragma unroll
        for (int i = 0; i < 4; ++i)
          smem[(o0 + i) * 72 + col] = f2bf(acc[m][n][i]);
      }
    __syncthreads();
    u16* dst = (z == 0) ? q : kmat;
    #pragma unroll
    for (int i = 0; i < 4; ++i) {
      int L = tid + 256 * i;                 // 0..1023: 128 rows x 8 chunks of 8
      int r = L >> 3, ch = L & 7;
      short8 vv = *(const short8*)&smem[r * 72 + ch * 8];
      *(short8*)&dst[(size_t)(b * CCH + r) * HW + hw0 + ch * 8] = vv;
    }
  } else {
    #pragma unroll
    for (int m = 0; m < 2; ++m)
      #pragma unroll
      for (int n = 0; n < 4; ++n) {
        int o0 = w * 32 + m * 16 + 4 * lg;
        int col = n * 16 + lr;
        ushort4 pv;
        pv.x = f2bf(acc[m][n][0]);
        pv.y = f2bf(acc[m][n][1]);
        pv.z = f2bf(acc[m][n][2]);
        pv.w = f2bf(acc[m][n][3]);
        *(ushort4*)&smem[col * 136 + o0] = pv;
      }
    __syncthreads();
    #pragma unroll
    for (int i = 0; i < 4; ++i) {
      int L = tid + 256 * i;                 // 0..1023: 64 rows x 16 chunks of 8
      int hw = L >> 4, ch = L & 15;
      short8 vv = *(const short8*)&smem[hw * 136 + ch * 8];
      *(short8*)&vt[(size_t)(hw0 + hw) * NROW + b * CCH + ch * 8] = vv;
    }
  }
}

// ---------------- 256x128 BK=64 single-buffer GEMM, 2 blocks/CU ----------------
// r10: bigger M-tile cuts staged-bytes/FLOP x0.75 and doubles MFMA per
// barrier-pair (64/wave). 4 waves (2x2), wave tile 128x64. LDS 48KB:
// A [256][64] at 0, B [128][64] at u16-offset 16384. Same XOR swizzle as r9.
// EPI=0: bf16 partial write (split-K); EPI=1: fp32 + resid (PV).
template <int MAP, int EPI>
__global__ __launch_bounds__(256, 2) void gemm4(
    const u16* __restrict__ A, const u16* __restrict__ BT,
    int lda, int N, int NT, int kstride, long long cstride_z,
    void* __restrict__ Cv, const float* __restrict__ resid) {
  __shared__ __align__(16) u16 smem[24576];   // 48 KiB
  const int tid = threadIdx.x;
  const int lane = tid & 63;
  const int wid = tid >> 6;
  const int wm = wid >> 1, wn = wid & 1;
  const int lr = lane & 15, lg = lane >> 4;

  // XCD-chunked tile maps (blockIdx.x & 7 = XCD)
  const int k = blockIdx.x & 7;
  const int j = blockIdx.x >> 3;
  int kz, by, bx;
  if (MAP == 0) {        // sim NSPLIT=4: grid 512 (8by x 16bx x 4kz); 2 XCD per kz
    kz = k >> 1; by = j & 7; bx = (k & 1) * 8 + (j >> 3);
  } else {               // PV: grid 576 (8by x 72bx); XCD = 8by x 9bx strip
    kz = 0; by = j & 7; bx = k * 9 + (j >> 3);
  }
  const int bm = by * 256, bn = bx * 128;

  const u16* Ag = A + (size_t)kz * kstride;
  const u16* Bg = BT + (size_t)kz * kstride;

  // staging: A 2048 chunks (8/thread), B 1024 chunks (4/thread); 16B each.
  // chunk qq: row = qq>>3, slot = qq&7; source col pre-swizzled, LDS dest linear.
  const u16* aS[8];
  u16* dA[8];
  #pragma unroll
  for (int i = 0; i < 8; ++i) {
    int qq = tid + 256 * i;
    int row = qq >> 3, slot = qq & 7;
    int ce = (slot ^ (row & 7)) * 8;
    aS[i] = Ag + (size_t)(bm + row) * lda + ce;
    dA[i] = smem + qq * 8;
  }
  const u16* bS[4];
  u16* dB[4];
  #pragma unroll
  for (int i = 0; i < 4; ++i) {
    int qq = tid + 256 * i;
    int row = qq >> 3, slot = qq & 7;
    int ce = (slot ^ (row & 7)) * 8;
    bS[i] = Bg + (size_t)(bn + row) * lda + ce;
    dB[i] = smem + 16384 + qq * 8;
  }

  const int kof0 = (lg * 8) ^ ((lr & 7) << 3);
  const int kof1 = (32 + lg * 8) ^ ((lr & 7) << 3);

  f32x4 acc[8][4] = {};

  for (int t = 0; t < NT; ++t) {
    const size_t ko = (size_t)t * 64;
    #pragma unroll
    for (int i = 0; i < 8; ++i) async16(aS[i] + ko, dA[i]);
    #pragma unroll
    for (int i = 0; i < 4; ++i) async16(bS[i] + ko, dB[i]);
    __syncthreads();                  // drains vmcnt -> tile visible
    short8 b[4][2];
    #pragma unroll
    for (int n = 0; n < 4; ++n) {
      const u16* p = smem + 16384 + (wn * 64 + n * 16 + lr) * 64;
      b[n][0] = *(const short8*)(p + kof0);
      b[n][1] = *(const short8*)(p + kof1);
    }
    #pragma unroll
    for (int mh = 0; mh < 2; ++mh) {  // two a-frag halves cap register use
      short8 a[4][2];
      #pragma unroll
      for (int m = 0; m < 4; ++m) {
        const u16* p = smem + (wm * 128 + (mh * 4 + m) * 16 + lr) * 64;
        a[m][0] = *(const short8*)(p + kof0);
        a[m][1] = *(const short8*)(p + kof1);
      }
      #pragma unroll
      for (int kk = 0; kk < 2; ++kk)
        #pragma unroll
        for (int m = 0; m < 4; ++m)
          #pragma unroll
          for (int n = 0; n < 4; ++n)
            acc[mh * 4 + m][n] = __builtin_amdgcn_mfma_f32_16x16x32_bf16(
                a[m][kk], b[n][kk], acc[mh * 4 + m][n], 0, 0, 0);
    }
    __syncthreads();                  // reads done before next stage overwrites
  }

  #pragma unroll
  for (int m = 0; m < 8; ++m) {
    #pragma unroll
    for (int n = 0; n < 4; ++n) {
      int row0 = bm + wm * 128 + m * 16 + 4 * lg;
      int col = bn + wn * 64 + n * 16 + lr;
      #pragma unroll
      for (int i = 0; i < 4; ++i) {
        size_t idx = (size_t)(row0 + i) * N + col;
        if (EPI == 1) {
          ((float*)Cv)[idx] = acc[m][n][i] + resid[idx];
        } else {
          ((u16*)Cv)[(size_t)kz * cstride_z + idx] = f2bf(acc[m][n][i]);
        }
      }
    }
  }
}

// ---------------- softmax over rows, summing 4 bf16 partials, emit bf16 P ----
__global__ __launch_bounds__(256) void softmax4_kernel(
    const u16* __restrict__ sim, u16* __restrict__ P) {
  const int row = blockIdx.x;
  const int t = threadIdx.x;
  const int lane = t & 63, w = t >> 6;
  float x[8] = {0.f, 0.f, 0.f, 0.f, 0.f, 0.f, 0.f, 0.f};
  #pragma unroll
  for (int s = 0; s < 4; ++s) {
    const u16* r = sim + (size_t)s * 4194304 + (size_t)row * NROW + t * 8;
    short8 a = *(const short8*)r;
    #pragma unroll
    for (int jj = 0; jj < 8; ++jj) x[jj] += bf2f((u16)a[jj]);
  }

  float m = x[0];
  #pragma unroll
  for (int jj = 1; jj < 8; ++jj) m = fmaxf(m, x[jj]);
  #pragma unroll
  for (int o = 1; o < 64; o <<= 1) m = fmaxf(m, __shfl_xor(m, o));
  __shared__ float redm[4], reds[4];
  if (lane == 0) redm[w] = m;
  __syncthreads();
  m = fmaxf(fmaxf(redm[0], redm[1]), fmaxf(redm[2], redm[3]));

  float e[8];
  float s = 0.f;
  #pragma unroll
  for (int jj = 0; jj < 8; ++jj) { e[jj] = __expf(x[jj] - m); s += e[jj]; }
  #pragma unroll
  for (int o = 1; o < 64; o <<= 1) s += __shfl_xor(s, o);
  if (lane == 0) reds[w] = s;
  __syncthreads();
  s = reds[0] + reds[1] + reds[2] + reds[3];
  float inv = 1.f / s;

  short8 pv;
  #pragma unroll
  for (int jj = 0; jj < 8; ++jj) pv[jj] = (short)f2bf(e[jj] * inv);
  *(short8*)(P + (size_t)row * NROW + t * 8) = pv;
}

// ---------------- launch ----------------
extern "C" void kernel_launch(void* const* d_in, const int* in_sizes, int n_in,
                              void* d_out, int out_size, void* d_ws, size_t ws_size,
                              hipStream_t stream) {
  const float* f_in = (const float*)d_in[0];
  const float* e_in = (const float*)d_in[1];
  const float* Wq = (const float*)d_in[2];
  const float* Wk = (const float*)d_in[3];
  const float* Wv = (const float*)d_in[4];
  float* out = (float*)d_out;
  char* ws = (char*)d_ws;

  u16* wq_bf = (u16*)(ws + 0);
  u16* wk_bf = (u16*)(ws + 32768);
  u16* wv_bf = (u16*)(ws + 65536);
  u16* q    = (u16*)(ws + 98304);                        // 2048x9216 bf16
  u16* kmat = (u16*)(ws + 98304 + 37748736ull);          // 2048x9216 bf16
  u16* vt   = (u16*)(ws + 98304 + 2 * 37748736ull);      // 9216x2048 bf16 (V^T)
  u16* sim  = (u16*)(ws + 98304 + 3 * 37748736ull);      // 4 x 2048x2048 bf16 partials
  u16* P    = q;                                         // overlay: q dead after sim GEMM

  wcvt_kernel<<<64, 256, 0, stream>>>(Wq, Wk, Wv, wq_bf, wk_bf, wv_bf);
  proj2_kernel<<<dim3(144, 16, 3), 256, 0, stream>>>(f_in, e_in, wq_bf, wk_bf, wv_bf, q, kmat, vt);
  // sim = q*k^T, split-K=4 (K=2304 each), bf16 partials, 256x128 tiles
  gemm4<0, 0><<<512, 256, 0, stream>>>(q, kmat, HW, NROW, 36, 2304, 4194304LL, sim, nullptr);
  softmax4_kernel<<<2048, 256, 0, stream>>>(sim, P);
  // out = P*v + f_in, 256x128 tiles
  gemm4<1, 1><<<576, 256, 0, stream>>>(P, vt, NROW, HW, 32, 0, 0LL, out, f_in);
}

// Round 11
// 240.838 us; speedup vs baseline: 1.1101x; 1.1101x over previous
//
#include <hip/hip_runtime.h>
#include <hip/hip_bf16.h>

typedef __attribute__((ext_vector_type(4))) float f32x4;
typedef __attribute__((ext_vector_type(8))) short short8;
typedef unsigned short u16;

typedef const __attribute__((address_space(1))) void* gas_ptr;
typedef __attribute__((address_space(3))) void* las_ptr;

#define HW 9216
#define NROW 2048
#define CCH 128

__device__ __forceinline__ u16 f2bf(float x) {
  unsigned u = __float_as_uint(x);
  u += 0x7fffu + ((u >> 16) & 1u);   // round-to-nearest-even
  return (u16)(u >> 16);
}

__device__ __forceinline__ float bf2f(u16 v) {
  return __uint_as_float(((unsigned)v) << 16);
}

__device__ __forceinline__ void async16(const void* g, void* l) {
  __builtin_amdgcn_global_load_lds((gas_ptr)g, (las_ptr)l, 16, 0, 0);
}

// ---------------- kernel 0: convert weights fp32 -> bf16 ----------------
__global__ __launch_bounds__(256) void wcvt_kernel(
    const float* __restrict__ wq, const float* __restrict__ wk, const float* __restrict__ wv,
    u16* __restrict__ oq, u16* __restrict__ ok, u16* __restrict__ ov) {
  int i = blockIdx.x * 256 + threadIdx.x;
  if (i < CCH * CCH) {
    oq[i] = f2bf(wq[i]);
    ok[i] = f2bf(wk[i]);
    ov[i] = f2bf(wv[i]);
  }
}

// ---------------- kernel 1 v2: projection, one of {q,k,v} per blockIdx.z ----
// (r7 verified) z=0: q = Wq*f; z=1: k = Wk*e; z=2: vt = (Wv*f)^T.
__global__ __launch_bounds__(256) void proj2_kernel(
    const float* __restrict__ f_in, const float* __restrict__ e_in,
    const u16* __restrict__ Wq, const u16* __restrict__ Wk, const u16* __restrict__ Wv,
    u16* __restrict__ q, u16* __restrict__ kmat, u16* __restrict__ vt) {
  __shared__ __align__(16) u16 smem[9216];   // 18KB: max(stage 64x128, out 128x72, outT 64x136)
  const int tid = threadIdx.x;
  const int lane = tid & 63;
  const int w = tid >> 6;                    // wave = o-band (32 rows)
  const int lr = lane & 15, lg = lane >> 4;
  const int z = blockIdx.z;
  const int b = blockIdx.y;
  const int hw0 = blockIdx.x * 64;

  const float* src = (z == 1) ? e_in : f_in;
  const u16* W = (z == 0) ? Wq : (z == 1) ? Wk : Wv;

  short8 afrag[2][4];
  #pragma unroll
  for (int m = 0; m < 2; ++m)
    #pragma unroll
    for (int kk = 0; kk < 4; ++kk)
      afrag[m][kk] = *(const short8*)(W + (w * 32 + m * 16 + lr) * CCH + kk * 32 + lg * 8);

  const size_t base = (size_t)b * CCH * HW + hw0;
  #pragma unroll
  for (int it = 0; it < 4; ++it) {
    int g = w + 4 * it;                      // c-block 0..15 (8 channels each)
    const float* sp = src + base + (size_t)(g * 8) * HW + lane;
    short8 sv;
    #pragma unroll
    for (int j = 0; j < 8; ++j) sv[j] = (short)f2bf(sp[(size_t)j * HW]);
    int gs = (g & 8) | ((g & 7) ^ (lane & 7));
    *(short8*)&smem[lane * 128 + gs * 8] = sv;
  }
  __syncthreads();

  f32x4 acc[2][4] = {};
  #pragma unroll
  for (int kk = 0; kk < 4; ++kk) {
    short8 bF[4];
    #pragma unroll
    for (int n = 0; n < 4; ++n) {
      int col = n * 16 + lr;
      int gidx = kk * 4 + lg;
      int gsw = (gidx & 8) | ((gidx & 7) ^ (col & 7));
      bF[n] = *(const short8*)&smem[col * 128 + gsw * 8];
    }
    #pragma unroll
    for (int m = 0; m < 2; ++m)
      #pragma unroll
      for (int n = 0; n < 4; ++n)
        acc[m][n] = __builtin_amdgcn_mfma_f32_16x16x32_bf16(afrag[m][kk], bF[n], acc[m][n], 0, 0, 0);
  }
  __syncthreads();   // all reads of staged tile done; reuse smem for output

  if (z < 2) {
    #pragma unroll
    for (int m = 0; m < 2; ++m)
      #pragma unroll
      for (int n = 0; n < 4; ++n) {
        int o0 = w * 32 + m * 16 + 4 * lg;
        int col = n * 16 + lr;
        #pragma unroll
        for (int i = 0; i < 4; ++i)
          smem[(o0 + i) * 72 + col] = f2bf(acc[m][n][i]);
      }
    __syncthreads();
    u16* dst = (z == 0) ? q : kmat;
    #pragma unroll
    for (int i = 0; i < 4; ++i) {
      int L = tid + 256 * i;                 // 0..1023: 128 rows x 8 chunks of 8
      int r = L >> 3, ch = L & 7;
      short8 vv = *(const short8*)&smem[r * 72 + ch * 8];
      *(short8*)&dst[(size_t)(b * CCH + r) * HW + hw0 + ch * 8] = vv;
    }
  } else {
    #pragma unroll
    for (int m = 0; m < 2; ++m)
      #pragma unroll
      for (int n = 0; n < 4; ++n) {
        int o0 = w * 32 + m * 16 + 4 * lg;
        int col = n * 16 + lr;
        ushort4 pv;
        pv.x = f2bf(acc[m][n][0]);
        pv.y = f2bf(acc[m][n][1]);
        pv.z = f2bf(acc[m][n][2]);
        pv.w = f2bf(acc[m][n][3]);
        *(ushort4*)&smem[col * 136 + o0] = pv;
      }
    __syncthreads();
    #pragma unroll
    for (int i = 0; i < 4; ++i) {
      int L = tid + 256 * i;                 // 0..1023: 64 rows x 16 chunks of 8
      int hw = L >> 4, ch = L & 15;
      short8 vv = *(const short8*)&smem[hw * 136 + ch * 8];
      *(short8*)&vt[(size_t)(hw0 + hw) * NROW + b * CCH + ch * 8] = vv;
    }
  }
}

// ---------------- 128x128 BK=64 single-buffer GEMM, 3+ blocks/CU (r9 winner) ----
// EPI=0: write bf16 partial (split-K, halves intermediate traffic)
// EPI=1: fp32 write + resid (PV epilogue)
template <int MAP, int EPI>
__global__ __launch_bounds__(256, 3) void gemm4(
    const u16* __restrict__ A, const u16* __restrict__ BT,
    int lda, int N, int NT, int kstride, long long cstride_z,
    void* __restrict__ Cv, const float* __restrict__ resid) {
  __shared__ __align__(16) u16 smem[16384];   // 32 KiB
  const int tid = threadIdx.x;
  const int lane = tid & 63;
  const int wid = tid >> 6;
  const int wm = wid >> 1, wn = wid & 1;
  const int lr = lane & 15, lg = lane >> 4;

  // XCD-chunked tile maps (blockIdx.x & 7 = XCD)
  const int k = blockIdx.x & 7;
  const int j = blockIdx.x >> 3;
  int kz, by, bx;
  if (MAP == 0) {        // sim NSPLIT=4: grid 1024; XCD = 8by x 16bx of one kz
    kz = k >> 1; by = (k & 1) * 8 + (j & 7); bx = j >> 3;
  } else {               // PV: grid 1152 (16by x 72bx); XCD = 8by x 18bx
    kz = 0; by = (k >> 2) * 8 + (j & 7); bx = (k & 3) * 18 + (j >> 3);
  }
  const int bm = by * 128, bn = bx * 128;

  const u16* Ag = A + (size_t)kz * kstride;
  const u16* Bg = BT + (size_t)kz * kstride;

  // staging: 1024 16B-chunks per matrix; chunk qq = tid + 256*i; row=qq>>3, slot=qq&7
  const u16* aS[4];
  const u16* bS[4];
  u16* dA[4];
  u16* dB[4];
  #pragma unroll
  for (int i = 0; i < 4; ++i) {
    int qq = tid + 256 * i;
    int row = qq >> 3, slot = qq & 7;
    int ce = (slot ^ (row & 7)) * 8;
    aS[i] = Ag + (size_t)(bm + row) * lda + ce;
    bS[i] = Bg + (size_t)(bn + row) * lda + ce;
    dA[i] = smem + qq * 8;
    dB[i] = smem + 8192 + qq * 8;
  }

  const int kof0 = (lg * 8) ^ ((lr & 7) << 3);
  const int kof1 = (32 + lg * 8) ^ ((lr & 7) << 3);

  f32x4 acc[4][4] = {};

  for (int t = 0; t < NT; ++t) {
    const size_t ko = (size_t)t * 64;
    #pragma unroll
    for (int i = 0; i < 4; ++i) { async16(aS[i] + ko, dA[i]); async16(bS[i] + ko, dB[i]); }
    __syncthreads();
    short8 a[4][2], b[4][2];
    #pragma unroll
    for (int m = 0; m < 4; ++m) {
      const u16* p = smem + (wm * 64 + m * 16 + lr) * 64;
      a[m][0] = *(const short8*)(p + kof0);
      a[m][1] = *(const short8*)(p + kof1);
    }
    #pragma unroll
    for (int n = 0; n < 4; ++n) {
      const u16* p = smem + 8192 + (wn * 64 + n * 16 + lr) * 64;
      b[n][0] = *(const short8*)(p + kof0);
      b[n][1] = *(const short8*)(p + kof1);
    }
    #pragma unroll
    for (int kk = 0; kk < 2; ++kk)
      #pragma unroll
      for (int m = 0; m < 4; ++m)
        #pragma unroll
        for (int n = 0; n < 4; ++n)
          acc[m][n] = __builtin_amdgcn_mfma_f32_16x16x32_bf16(a[m][kk], b[n][kk], acc[m][n], 0, 0, 0);
    __syncthreads();
  }

  #pragma unroll
  for (int m = 0; m < 4; ++m) {
    #pragma unroll
    for (int n = 0; n < 4; ++n) {
      int row0 = bm + wm * 64 + m * 16 + 4 * lg;
      int col = bn + wn * 64 + n * 16 + lr;
      #pragma unroll
      for (int i = 0; i < 4; ++i) {
        size_t idx = (size_t)(row0 + i) * N + col;
        if (EPI == 1) {
          ((float*)Cv)[idx] = acc[m][n][i] + resid[idx];
        } else {
          ((u16*)Cv)[(size_t)kz * cstride_z + idx] = f2bf(acc[m][n][i]);
        }
      }
    }
  }
}

// ---------------- softmax over rows, summing 4 bf16 partials, emit bf16 P ----
__global__ __launch_bounds__(256) void softmax4_kernel(
    const u16* __restrict__ sim, u16* __restrict__ P) {
  const int row = blockIdx.x;
  const int t = threadIdx.x;
  const int lane = t & 63, w = t >> 6;
  float x[8] = {0.f, 0.f, 0.f, 0.f, 0.f, 0.f, 0.f, 0.f};
  #pragma unroll
  for (int s = 0; s < 4; ++s) {
    const u16* r = sim + (size_t)s * 4194304 + (size_t)row * NROW + t * 8;
    short8 a = *(const short8*)r;
    #pragma unroll
    for (int jj = 0; jj < 8; ++jj) x[jj] += bf2f((u16)a[jj]);
  }

  float m = x[0];
  #pragma unroll
  for (int jj = 1; jj < 8; ++jj) m = fmaxf(m, x[jj]);
  #pragma unroll
  for (int o = 1; o < 64; o <<= 1) m = fmaxf(m, __shfl_xor(m, o));
  __shared__ float redm[4], reds[4];
  if (lane == 0) redm[w] = m;
  __syncthreads();
  m = fmaxf(fmaxf(redm[0], redm[1]), fmaxf(redm[2], redm[3]));

  float e[8];
  float s = 0.f;
  #pragma unroll
  for (int jj = 0; jj < 8; ++jj) { e[jj] = __expf(x[jj] - m); s += e[jj]; }
  #pragma unroll
  for (int o = 1; o < 64; o <<= 1) s += __shfl_xor(s, o);
  if (lane == 0) reds[w] = s;
  __syncthreads();
  s = reds[0] + reds[1] + reds[2] + reds[3];
  float inv = 1.f / s;

  short8 pv;
  #pragma unroll
  for (int jj = 0; jj < 8; ++jj) pv[jj] = (short)f2bf(e[jj] * inv);
  *(short8*)(P + (size_t)row * NROW + t * 8) = pv;
}

// ---------------- launch ----------------
extern "C" void kernel_launch(void* const* d_in, const int* in_sizes, int n_in,
                              void* d_out, int out_size, void* d_ws, size_t ws_size,
                              hipStream_t stream) {
  const float* f_in = (const float*)d_in[0];
  const float* e_in = (const float*)d_in[1];
  const float* Wq = (const float*)d_in[2];
  const float* Wk = (const float*)d_in[3];
  const float* Wv = (const float*)d_in[4];
  float* out = (float*)d_out;
  char* ws = (char*)d_ws;

  u16* wq_bf = (u16*)(ws + 0);
  u16* wk_bf = (u16*)(ws + 32768);
  u16* wv_bf = (u16*)(ws + 65536);
  u16* q    = (u16*)(ws + 98304);                        // 2048x9216 bf16
  u16* kmat = (u16*)(ws + 98304 + 37748736ull);          // 2048x9216 bf16
  u16* vt   = (u16*)(ws + 98304 + 2 * 37748736ull);      // 9216x2048 bf16 (V^T)
  u16* sim  = (u16*)(ws + 98304 + 3 * 37748736ull);      // 4 x 2048x2048 bf16 partials
  u16* P    = q;                                         // overlay: q dead after sim GEMM

  wcvt_kernel<<<64, 256, 0, stream>>>(Wq, Wk, Wv, wq_bf, wk_bf, wv_bf);
  proj2_kernel<<<dim3(144, 16, 3), 256, 0, stream>>>(f_in, e_in, wq_bf, wk_bf, wv_bf, q, kmat, vt);
  // sim = q*k^T, split-K=4 (K=2304 each), bf16 partials
  gemm4<0, 0><<<1024, 256, 0, stream>>>(q, kmat, HW, NROW, 36, 2304, 4194304LL, sim, nullptr);
  softmax4_kernel<<<2048, 256, 0, stream>>>(sim, P);
  // out = P*v + f_in
  gemm4<1, 1><<<1152, 256, 0, stream>>>(P, vt, NROW, HW, 32, 0, 0LL, out, f_in);
}